// Round 1
// baseline (329.086 us; speedup 1.0000x reference)
//
#include <hip/hip_runtime.h>

// Problem constants (match reference file)
#define N_NODES 500000
#define DIM     128       // hidden channels
#define BATCH   8192      // triplets
#define KNB     64        // neighbors per disease
#define LAMBDA  0.7f

// ---------------------------------------------------------------------------
// Kernel 1: tag[n] = -1 for all nodes (don't rely on ws poison value)
// ---------------------------------------------------------------------------
__global__ void k_init_tag(int* __restrict__ tag) {
    int i = blockIdx.x * blockDim.x + threadIdx.x;
    if (i < N_NODES) tag[i] = -1;
}

// ---------------------------------------------------------------------------
// Kernel 2: tag[head[b]] = max b  (last-write-wins winner per node)
// ---------------------------------------------------------------------------
__global__ void k_tag(const int* __restrict__ head, int* __restrict__ tag) {
    int b = blockIdx.x * blockDim.x + threadIdx.x;
    if (b < BATCH) atomicMax(&tag[head[b]], b);
}

// ---------------------------------------------------------------------------
// Per-wave: compute node_emb2[node] (post-scatter row), 2 dims per lane.
// All branches are wave-uniform (node/winner uniform across the wave).
// ---------------------------------------------------------------------------
__device__ __forceinline__ float2 emb2_row(
    int node, int lane,
    const int*   __restrict__ tag,
    const int*   __restrict__ rel_type,
    const float* __restrict__ node_emb,
    const int*   __restrict__ local_idx_map,
    const int*   __restrict__ sim_neighbors,
    const float* __restrict__ sim_weights,
    const int*   __restrict__ degree_table)
{
    const float2* row = (const float2*)(node_emb + (size_t)node * DIM);
    float2 old = row[lane];

    int w = tag[node];
    if (w < 0) return old;              // node never written
    int rt = rel_type[w];
    if (rt < 2 || rt > 4) return old;   // winner unmasked -> wrote back old

    // winner is masked: recompute its update row
    int   loc = local_idx_map[node];    // head[w] == node by construction
    float deg = (float)degree_table[loc * 3 + (rt - 2)];
    float c   = LAMBDA * expf(-LAMBDA * deg) + 0.2f;

    // lane k holds neighbor k's id/weight; broadcast via shfl (K == wave width)
    int   nb = sim_neighbors[(size_t)loc * KNB + lane];
    float wt = sim_weights  [(size_t)loc * KNB + lane];

    float2 acc = make_float2(0.0f, 0.0f);
    #pragma unroll 4
    for (int k = 0; k < KNB; ++k) {
        int   n_k = __shfl(nb, k, 64);
        float w_k = __shfl(wt, k, 64);
        const float2* vrow = (const float2*)(node_emb + (size_t)n_k * DIM);
        float2 v = vrow[lane];
        acc.x += w_k * v.x;
        acc.y += w_k * v.y;
    }
    return make_float2(c * acc.x + (1.0f - c) * old.x,
                       c * acc.y + (1.0f - c) * old.y);
}

// ---------------------------------------------------------------------------
// Kernel 3: one wave per triplet -> DistMult score
// ---------------------------------------------------------------------------
__global__ __launch_bounds__(256)
void k_score(const int*   __restrict__ head,
             const int*   __restrict__ rel_type,
             const int*   __restrict__ tail,
             const float* __restrict__ node_emb,
             const float* __restrict__ rel_emb,
             const int*   __restrict__ local_idx_map,
             const int*   __restrict__ sim_neighbors,
             const float* __restrict__ sim_weights,
             const int*   __restrict__ degree_table,
             const int*   __restrict__ tag,
             float*       __restrict__ out)
{
    int lane = threadIdx.x & 63;
    int wid  = threadIdx.x >> 6;
    int b    = blockIdx.x * (blockDim.x >> 6) + wid;
    if (b >= BATCH) return;

    int h = head[b];
    int t = tail[b];
    int r = rel_type[b];

    float2 hv = emb2_row(h, lane, tag, rel_type, node_emb,
                         local_idx_map, sim_neighbors, sim_weights, degree_table);
    float2 tv = emb2_row(t, lane, tag, rel_type, node_emb,
                         local_idx_map, sim_neighbors, sim_weights, degree_table);

    const float2* rrow = (const float2*)(rel_emb + (size_t)r * DIM);
    float2 rv = rrow[lane];

    float p = hv.x * rv.x * tv.x + hv.y * rv.y * tv.y;

    // wave-64 reduction
    #pragma unroll
    for (int off = 32; off > 0; off >>= 1)
        p += __shfl_down(p, off, 64);

    if (lane == 0) out[b] = p;
}

// ---------------------------------------------------------------------------
// kernel_launch
// d_in order: head_index, rel_type, tail_index, node_emb, rel_emb,
//             local_idx_map, sim_neighbors, sim_weights, degree_table
// ---------------------------------------------------------------------------
extern "C" void kernel_launch(void* const* d_in, const int* in_sizes, int n_in,
                              void* d_out, int out_size, void* d_ws, size_t ws_size,
                              hipStream_t stream) {
    const int*   head     = (const int*)  d_in[0];
    const int*   rel_type = (const int*)  d_in[1];
    const int*   tail     = (const int*)  d_in[2];
    const float* node_emb = (const float*)d_in[3];
    const float* rel_emb  = (const float*)d_in[4];
    const int*   lmap     = (const int*)  d_in[5];
    const int*   sn       = (const int*)  d_in[6];
    const float* sw       = (const float*)d_in[7];
    const int*   dt       = (const int*)  d_in[8];
    float*       out      = (float*)      d_out;

    int* tag = (int*)d_ws;   // N_NODES ints = 2 MB

    k_init_tag<<<(N_NODES + 255) / 256, 256, 0, stream>>>(tag);
    k_tag<<<(BATCH + 255) / 256, 256, 0, stream>>>(head, tag);
    // 4 waves per 256-thread block, one wave per triplet
    k_score<<<BATCH / 4, 256, 0, stream>>>(head, rel_type, tail,
                                           node_emb, rel_emb, lmap, sn, sw, dt,
                                           tag, out);
}